// Round 9
// baseline (73.473 us; speedup 1.0000x reference)
//
#include <hip/hip_runtime.h>

#define GAT_ALPHA 0.2f
#define INV_N (1.0f / 2048.0f)

typedef float f32x4 __attribute__((ext_vector_type(4)));
typedef int   i32x4 __attribute__((ext_vector_type(4)));
typedef __bf16 bf16x8 __attribute__((ext_vector_type(8)));
typedef unsigned short us8 __attribute__((ext_vector_type(8)));
typedef unsigned short us4 __attribute__((ext_vector_type(4)));

__device__ __forceinline__ unsigned short f2bf(float x) {
  union { float f; unsigned u; } v; v.f = x;
  unsigned r = v.u + 0x7FFFu + ((v.u >> 16) & 1u);   // RNE
  return (unsigned short)(r >> 16);
}
__device__ __forceinline__ float lrelu(float x) {
  return fmaxf(x, 0.f) + GAT_ALPHA * fminf(x, 0.f);
}
__device__ __forceinline__ void lgkm_barrier() {
  asm volatile("s_waitcnt lgkmcnt(0)" ::: "memory");
  __builtin_amdgcn_s_barrier();
  __builtin_amdgcn_sched_barrier(0);
}

// ---------------- k0: Wh = h @ W (f32), s1/s2, WhT in bf16 [b][f][j] ----------------
__global__ __launch_bounds__(256)
void k0_wh(const float* __restrict__ h, const float* __restrict__ W,
           const float* __restrict__ a, unsigned short* __restrict__ WhT,
           float* __restrict__ s1g, float* __restrict__ s2g)
{
  __shared__ float h_s[64][132];
  __shared__ float W_s[128][64];
  __shared__ float wt_s[64][66];
  __shared__ float a_s[128];
  const int t = threadIdx.x;
  const int b = blockIdx.y;
  const int r0 = blockIdx.x * 64;

#pragma unroll
  for (int v = 0; v < 8; ++v) {
    int c = v * 256 + t;
    int k = c >> 4, fo = (c & 15) << 2;
    *(float4*)&W_s[k][fo] = *(const float4*)&W[k * 64 + fo];
  }
#pragma unroll
  for (int v = 0; v < 8; ++v) {
    int c = v * 256 + t;
    int r = c >> 5, ko = (c & 31) << 2;
    *(float4*)&h_s[r][ko] = *(const float4*)&h[((size_t)(b * 2048 + r0 + r)) * 128 + ko];
  }
  if (t < 128) a_s[t] = a[t];
  __syncthreads();

  const int tg = t >> 4;          // 0..15
  const int tf = (t & 15) << 2;   // f base
  float acc[4][4] = {};
#pragma unroll
  for (int k4 = 0; k4 < 32; ++k4) {
    float4 hv[4];
#pragma unroll
    for (int i = 0; i < 4; ++i)
      hv[i] = *(const float4*)&h_s[i * 16 + tg][k4 * 4];
#pragma unroll
    for (int kk = 0; kk < 4; ++kk) {
      float4 wv = *(const float4*)&W_s[k4 * 4 + kk][tf];
#pragma unroll
      for (int i = 0; i < 4; ++i) {
        float hx = ((const float*)&hv[i])[kk];
        acc[i][0] = fmaf(hx, wv.x, acc[i][0]);
        acc[i][1] = fmaf(hx, wv.y, acc[i][1]);
        acc[i][2] = fmaf(hx, wv.z, acc[i][2]);
        acc[i][3] = fmaf(hx, wv.w, acc[i][3]);
      }
    }
  }
#pragma unroll
  for (int i = 0; i < 4; ++i)
#pragma unroll
    for (int j = 0; j < 4; ++j)
      wt_s[tf + j][i * 16 + tg] = acc[i][j];
  __syncthreads();

  if (t < 64) {   // s1/s2 for row r = t (f32 exact)
    float v1 = 0.f, v2 = 0.f;
#pragma unroll 8
    for (int f = 0; f < 64; ++f) {
      float w = wt_s[f][t];
      v1 = fmaf(w, a_s[f], v1);
      v2 = fmaf(w, a_s[64 + f], v2);
    }
    s1g[b * 2048 + r0 + t] = v1;
    s2g[b * 2048 + r0 + t] = v2;
  }
  {  // WhT bf16 write, [b][f][j]
    int f = t >> 2, rb = (t & 3) << 4;
    unsigned short pk[16];
#pragma unroll
    for (int i = 0; i < 16; ++i) pk[i] = f2bf(wt_s[f][rb + i]);
    size_t base = ((size_t)(b * 64 + f)) * 2048 + r0 + rb;
    *(uint4*)&WhT[base]     = *(uint4*)&pk[0];
    *(uint4*)&WhT[base + 8] = *(uint4*)&pk[8];
  }
}

// ---------------- k12: fused stats + att write (nt) + PV MFMA + ELU ----------------
// 16-row strips, 1024 blocks (4/CU). Pass 1: stream adj (cached, double-buffered
// 8-int4 in flight), masks -> bm16 LDS, denom via 16-lane shuffle. Pass 2: R8's
// proven loop (T14 wh staging, nt att stores, us4 att_s stash, lgkm barriers),
// full j-range -> direct hout + ELU epilogue. No gmask, no pp, no k3.
__global__ __launch_bounds__(256, 4)
void k12_main(const int* __restrict__ adj, const unsigned short* __restrict__ WhT,
              const float* __restrict__ s1g, const float* __restrict__ s2g,
              float* __restrict__ hout, float* __restrict__ att)
{
  __shared__ float z_s[2048];                 // 8 KB
  __shared__ unsigned short bm16[16][128];    // 4 KB: bit (j&15) of word j>>4
  __shared__ float s1_s[16], il_s[16];
  __shared__ unsigned short att_s[16][136];   // bf16 att tile (stride 272 B)
  __shared__ unsigned short wh_s[64][136];    // bf16 Wh tile [f][k]

  const int t = threadIdx.x;
  const int b = blockIdx.y;
  const int r0 = blockIdx.x * 16;
  const size_t rowb = (size_t)(b * 2048 + r0);
  const int r = t >> 4, q = t & 15;           // pass-1: 16 threads per row
  const int* __restrict__ arow = adj + (rowb + r) * 2048;

  // issue first adj batch BEFORE staging barrier (loads fly across lgkm_barrier)
  i32x4 av0[4], av1[4];
#pragma unroll
  for (int k = 0; k < 4; ++k) av0[k] = *(const i32x4*)&arow[q * 16 + 4 * k];

  // stage z_s (s2 row, 2048 f32) + s1_s
  *(float4*)&z_s[t * 8]     = *(const float4*)&s2g[b * 2048 + t * 8];
  *(float4*)&z_s[t * 8 + 4] = *(const float4*)&s2g[b * 2048 + t * 8 + 4];
  if (t < 16) s1_s[t] = s1g[rowb + t];
  const float s1v = s1g[rowb + r];
  lgkm_barrier();   // z_s visible; adj loads still in flight

  // ---- pass 1: masks + denominator (8 int4 in flight via double buffer) ----
  float sum = 0.f;
#pragma unroll
  for (int c = 0; c < 8; ++c) {
    if (c < 7) {
#pragma unroll
      for (int k = 0; k < 4; ++k)
        av1[k] = *(const i32x4*)&arow[(c + 1) * 256 + q * 16 + 4 * k];
    }
    unsigned bits = 0;
#pragma unroll
    for (int k = 0; k < 4; ++k) {
      const float4 z = *(const float4*)&z_s[c * 256 + q * 16 + 4 * k];
      const bool p0 = av0[k].x > 0, p1 = av0[k].y > 0;
      const bool p2 = av0[k].z > 0, p3 = av0[k].w > 0;
      bits |= (unsigned(p0) | (unsigned(p1) << 1) |
               (unsigned(p2) << 2) | (unsigned(p3) << 3)) << (4 * k);
      sum += p0 ? __expf(lrelu(s1v + z.x)) : 0.f;
      sum += p1 ? __expf(lrelu(s1v + z.y)) : 0.f;
      sum += p2 ? __expf(lrelu(s1v + z.z)) : 0.f;
      sum += p3 ? __expf(lrelu(s1v + z.w)) : 0.f;
    }
    bm16[r][c * 16 + q] = (unsigned short)bits;
#pragma unroll
    for (int k = 0; k < 4; ++k) av0[k] = av1[k];
  }
#pragma unroll
  for (int o = 1; o < 16; o <<= 1) sum += __shfl_xor(sum, o);
  if (q == 0) il_s[r] = (sum > 0.f) ? 1.f / sum : -1.f;  // -1: no neighbors -> 1/N
  lgkm_barrier();   // bm16 + il_s visible

  // ---- pass 2: att write (nt) + PV (R8 structure, 16 rows, full j) ----
  const int w  = t >> 6, l = t & 63;
  const int ln = l & 15, lg = l >> 4;
  const int ff = t >> 4, ko = (t & 15) << 3;   // wh staging coords
  f32x4 acc = {0.f, 0.f, 0.f, 0.f};

  for (int j0 = 0; j0 < 2048; j0 += 128) {
    // T14: issue WhT loads early, LDS-write late
    uint4 wreg[4];
#pragma unroll
    for (int v = 0; v < 4; ++v)
      wreg[v] = *(const uint4*)&WhT[((size_t)(b * 64 + v * 16 + ff)) * 2048 + j0 + ko];

    // attention: 16 rows x 128 j, 8 elements per thread
#pragma unroll
    for (int it = 0; it < 2; ++it) {
      const int rr = (t >> 5) + (it << 3);
      const int jj = (t & 31) << 2;
      const int j  = j0 + jj;
      const float s1r = s1_s[rr], il = il_s[rr];
      const bool uni = (il < 0.f);
      const unsigned mb = (unsigned)bm16[rr][j >> 4] >> (j & 15);
      const float4 zv = *(const float4*)&z_s[j];
      f32x4 o;
#define PW(dst, zz, k)                                              \
      { float e = __expf(lrelu(s1r + (zz))) * il;                   \
        dst = uni ? INV_N : (((mb >> (k)) & 1u) ? e : 0.f); }
      PW(o[0], zv.x, 0) PW(o[1], zv.y, 1) PW(o[2], zv.z, 2) PW(o[3], zv.w, 3)
#undef PW
      __builtin_nontemporal_store(o, (f32x4*)&att[(rowb + rr) * 2048 + j]);
      us4 pk;
      pk.x = f2bf(o[0]); pk.y = f2bf(o[1]); pk.z = f2bf(o[2]); pk.w = f2bf(o[3]);
      *(us4*)&att_s[rr][jj] = pk;
    }
    // late LDS write of Wh tile
#pragma unroll
    for (int v = 0; v < 4; ++v)
      *(uint4*)&wh_s[v * 16 + ff][ko] = wreg[v];

    lgkm_barrier();   // publish att_s + wh_s; nt att stores NOT drained
    // PV: wave w owns f-tile w; same k-permutation on both operands
#pragma unroll
    for (int ks = 0; ks < 4; ++ks) {
      union { us8 u; bf16x8 v; } ac, bc;
      ac.u = *(const us8*)&att_s[ln][ks * 32 + lg * 8];
      bc.u = *(const us8*)&wh_s[w * 16 + ln][ks * 32 + lg * 8];
      acc = __builtin_amdgcn_mfma_f32_16x16x32_bf16(ac.v, bc.v, acc, 0, 0, 0);
    }
    lgkm_barrier();   // LDS reads done before next overwrite
  }

  // epilogue: ELU. C/D layout: col(N=f)=lane&15, row(M)=4*(lane>>4)+reg
#pragma unroll
  for (int qq = 0; qq < 4; ++qq) {
    const int rr = lg * 4 + qq;
    const float x = acc[qq];
    hout[(rowb + rr) * 64 + w * 16 + ln] = (x > 0.f) ? x : expm1f(x);
  }
}

extern "C" void kernel_launch(void* const* d_in, const int* in_sizes, int n_in,
                              void* d_out, int out_size, void* d_ws, size_t ws_size,
                              hipStream_t stream)
{
  const float* h   = (const float*)d_in[0];
  const int*   adj = (const int*)d_in[1];
  const float* W   = (const float*)d_in[2];
  const float* a   = (const float*)d_in[3];
  float* hout = (float*)d_out;
  float* att  = hout + (size_t)8 * 2048 * 64;

  char* ws = (char*)d_ws;
  unsigned short* WhT = (unsigned short*)ws;                    // 2 MB
  float* s1 = (float*)(ws + (size_t)(2u << 20));                // 64 KB each
  float* s2 = s1 + 16384;

  k0_wh   <<<dim3(32, 8),  256, 0, stream>>>(h, W, a, WhT, s1, s2);
  k12_main<<<dim3(128, 8), 256, 0, stream>>>(adj, WhT, s1, s2, hout, att);
}